// Round 1
// baseline (960.793 us; speedup 1.0000x reference)
//
#include <hip/hip_runtime.h>

// Problem: dv = (-v + segment_sum(w * relu(v[src]) * tp[ntype[src]], dst) + stim + Vrest) / tau
// N_NODES = 500000, N_EDGES = 16000000, N_TYPES = 64
// edge_index is (2, N_EDGES) flat: src = base[0..E), dst = base[E..2E)
// Harness passes integer inputs as int32.

__global__ void node_pre_kernel(const float* __restrict__ v,
                                const int* __restrict__ ntype,
                                const float* __restrict__ tp,
                                float* __restrict__ g,
                                float* __restrict__ msg,
                                int n) {
    int i = blockIdx.x * blockDim.x + threadIdx.x;
    if (i < n) {
        float x = v[i];
        x = x > 0.0f ? x : 0.0f;
        g[i] = x * tp[ntype[i]];
        msg[i] = 0.0f;  // ws is poisoned 0xAA before every launch; self-zero
    }
}

// 4 edges per thread via vector loads: 3 streams (src, dst, w) are the HBM-bound part.
__global__ void edge_scatter_kernel(const int* __restrict__ src,
                                    const int* __restrict__ dst,
                                    const float* __restrict__ w,
                                    const float* __restrict__ g,
                                    float* __restrict__ msg,
                                    int n_vec) {
    int i = blockIdx.x * blockDim.x + threadIdx.x;
    if (i < n_vec) {
        int4   s  = ((const int4*)src)[i];
        int4   d  = ((const int4*)dst)[i];
        float4 wv = ((const float4*)w)[i];
        atomicAdd(&msg[d.x], wv.x * g[s.x]);
        atomicAdd(&msg[d.y], wv.y * g[s.y]);
        atomicAdd(&msg[d.z], wv.z * g[s.z]);
        atomicAdd(&msg[d.w], wv.w * g[s.w]);
    }
}

__global__ void edge_scatter_tail(const int* __restrict__ src,
                                  const int* __restrict__ dst,
                                  const float* __restrict__ w,
                                  const float* __restrict__ g,
                                  float* __restrict__ msg,
                                  int start, int n_edges) {
    int i = start + blockIdx.x * blockDim.x + threadIdx.x;
    if (i < n_edges) {
        atomicAdd(&msg[dst[i]], w[i] * g[src[i]]);
    }
}

__global__ void node_post_kernel(const float* __restrict__ v,
                                 const float* __restrict__ msg,
                                 const float* __restrict__ stim,
                                 const float* __restrict__ vrest,
                                 const float* __restrict__ tau,
                                 float* __restrict__ out,
                                 int n) {
    int i = blockIdx.x * blockDim.x + threadIdx.x;
    if (i < n) {
        out[i] = (-v[i] + msg[i] + stim[i] + vrest[i]) / tau[i];
    }
}

extern "C" void kernel_launch(void* const* d_in, const int* in_sizes, int n_in,
                              void* d_out, int out_size, void* d_ws, size_t ws_size,
                              hipStream_t stream) {
    const float* voltage   = (const float*)d_in[0];
    const float* stimulus  = (const float*)d_in[1];
    const int*   ntype     = (const int*)d_in[2];
    const int*   edge_idx  = (const int*)d_in[3];
    const float* w         = (const float*)d_in[4];
    const float* vrest     = (const float*)d_in[5];
    const float* tau       = (const float*)d_in[6];
    const float* tp        = (const float*)d_in[7];
    float* out = (float*)d_out;

    const int n_nodes = in_sizes[0];
    const int n_edges = in_sizes[4];
    const int* src = edge_idx;
    const int* dst = edge_idx + n_edges;

    float* g   = (float*)d_ws;            // n_nodes floats
    float* msg = (float*)d_ws + n_nodes;  // n_nodes floats

    const int B = 256;

    // 1) per-node precompute + zero accumulator
    node_pre_kernel<<<(n_nodes + B - 1) / B, B, 0, stream>>>(
        voltage, ntype, tp, g, msg, n_nodes);

    // 2) edge scatter (vectorized 4-wide)
    int n_vec = n_edges / 4;
    if (n_vec > 0) {
        edge_scatter_kernel<<<(n_vec + B - 1) / B, B, 0, stream>>>(
            src, dst, w, g, msg, n_vec);
    }
    int rem_start = n_vec * 4;
    if (rem_start < n_edges) {
        int rem = n_edges - rem_start;
        edge_scatter_tail<<<(rem + B - 1) / B, B, 0, stream>>>(
            src, dst, w, g, msg, rem_start, n_edges);
    }

    // 3) epilogue
    node_post_kernel<<<(n_nodes + B - 1) / B, B, 0, stream>>>(
        voltage, msg, stimulus, vrest, tau, out, n_nodes);
}

// Round 2
// 800.202 us; speedup vs baseline: 1.2007x; 1.2007x over previous
//
#include <hip/hip_runtime.h>

// dv = (-v + segment_sum(w * relu(v[src]) * tp[ntype[src]], dst) + stim + Vrest) / tau
// N_NODES = 500000, N_EDGES = 16000000.  edge_index flat: src = [0,E), dst = [E,2E).
//
// Round-1 lesson: 16M device-scope fp32 atomics serialize at the memory-side
// fabric (~20 G/s, 32 B RMW each) -> 785 us. This version bin-sorts edges by
// dst bucket (512 nodes/bucket) with deterministic prefix-sum offsets, then
// accumulates each bucket in LDS. No device-scope atomics anywhere.

#define BSHIFT 9
#define BSIZE  512              // nodes per bucket (LDS fp32 slice = 2 KB)
#define NB_PAD 1024             // LDS histogram/cursor array size (>= nb)
#define GPB    2048             // int4 groups per block = 8192 edges/block

// ---------------- main-path kernels ----------------

__global__ void pre_g_kernel(const float* __restrict__ v,
                             const int* __restrict__ ntype,
                             const float* __restrict__ tp,
                             float* __restrict__ g, int n) {
    int i = blockIdx.x * blockDim.x + threadIdx.x;
    if (i < n) {
        float x = v[i];
        x = x > 0.0f ? x : 0.0f;
        g[i] = x * tp[ntype[i]];
    }
}

__global__ void hist_kernel(const int* __restrict__ dst,
                            unsigned* __restrict__ cnt,
                            int G, int n_edges, int nblk, int nb) {
    __shared__ unsigned hist[NB_PAD];
    int blk = blockIdx.x, tid = threadIdx.x;
    for (int i = tid; i < NB_PAD; i += 256) hist[i] = 0;
    __syncthreads();
    const int4* d4 = (const int4*)dst;
    int gstart = blk * GPB;
    int gend = gstart + GPB; if (gend > G) gend = G;
    for (int i = gstart + tid; i < gend; i += 256) {
        int4 d = d4[i];
        atomicAdd(&hist[((unsigned)d.x) >> BSHIFT], 1u);
        atomicAdd(&hist[((unsigned)d.y) >> BSHIFT], 1u);
        atomicAdd(&hist[((unsigned)d.z) >> BSHIFT], 1u);
        atomicAdd(&hist[((unsigned)d.w) >> BSHIFT], 1u);
    }
    if (blk == nblk - 1) {
        for (int i = G * 4 + tid; i < n_edges; i += 256)
            atomicAdd(&hist[((unsigned)dst[i]) >> BSHIFT], 1u);
    }
    __syncthreads();
    for (int b = tid; b < nb; b += 256)
        cnt[(size_t)b * nblk + blk] = hist[b];
}

// grid = nb blocks; block b turns cnt[b][*] into an exclusive prefix (in place)
// and writes total[b].
__global__ void scan_blocks_kernel(unsigned* __restrict__ cnt,
                                   unsigned* __restrict__ total, int nblk) {
    __shared__ unsigned buf[256];
    __shared__ unsigned carry;
    int b = blockIdx.x, tid = threadIdx.x;
    if (tid == 0) carry = 0;
    __syncthreads();
    unsigned* row = cnt + (size_t)b * nblk;
    for (int i0 = 0; i0 < nblk; i0 += 256) {
        int i = i0 + tid;
        unsigned v = (i < nblk) ? row[i] : 0u;
        buf[tid] = v;
        __syncthreads();
        for (int o = 1; o < 256; o <<= 1) {
            unsigned t = (tid >= o) ? buf[tid - o] : 0u;
            __syncthreads();
            buf[tid] += t;
            __syncthreads();
        }
        unsigned excl = buf[tid] - v;
        if (i < nblk) row[i] = carry + excl;
        __syncthreads();                 // everyone read carry before update
        if (tid == 255) carry += buf[255];
        __syncthreads();
    }
    if (tid == 0) total[b] = carry;
}

// single block: exclusive scan of total[0..nb) -> base[0..nb)
__global__ void scan_buckets_kernel(const unsigned* __restrict__ total,
                                    unsigned* __restrict__ base, int nb) {
    __shared__ unsigned buf[256];
    int tid = threadIdx.x;
    unsigned v[4];
    unsigned s = 0;
    for (int k = 0; k < 4; k++) {
        int i = tid * 4 + k;
        v[k] = (i < nb) ? total[i] : 0u;
        s += v[k];
    }
    buf[tid] = s;
    __syncthreads();
    for (int o = 1; o < 256; o <<= 1) {
        unsigned t = (tid >= o) ? buf[tid - o] : 0u;
        __syncthreads();
        buf[tid] += t;
        __syncthreads();
    }
    unsigned run = buf[tid] - s;
    for (int k = 0; k < 4; k++) {
        int i = tid * 4 + k;
        if (i < nb) base[i] = run;
        run += v[k];
    }
}

// grid = nblk; scatter packed (val mantissa-high | local dst) into bucket
// segments, positions assigned by LDS cursors (CU-local atomics only).
__global__ void scatter_kernel(const int* __restrict__ src,
                               const int* __restrict__ dst,
                               const float* __restrict__ w,
                               const float* __restrict__ g,
                               const unsigned* __restrict__ base,
                               const unsigned* __restrict__ cnt,
                               unsigned* __restrict__ sorted,
                               int G, int n_edges, int nblk, int nb) {
    __shared__ unsigned cursor[NB_PAD];
    int blk = blockIdx.x, tid = threadIdx.x;
    for (int b = tid; b < nb; b += 256)
        cursor[b] = base[b] + cnt[(size_t)b * nblk + blk];
    __syncthreads();
    const int4* s4 = (const int4*)src;
    const int4* d4 = (const int4*)dst;
    const float4* w4 = (const float4*)w;
    int gstart = blk * GPB;
    int gend = gstart + GPB; if (gend > G) gend = G;
    for (int i = gstart + tid; i < gend; i += 256) {
        int4 s = s4[i]; int4 d = d4[i]; float4 wv = w4[i];
        {
            unsigned b = ((unsigned)d.x) >> BSHIFT;
            unsigned pos = atomicAdd(&cursor[b], 1u);
            float val = wv.x * g[s.x];
            sorted[pos] = (__float_as_uint(val) & ~(unsigned)(BSIZE - 1)) |
                          ((unsigned)d.x & (BSIZE - 1));
        }
        {
            unsigned b = ((unsigned)d.y) >> BSHIFT;
            unsigned pos = atomicAdd(&cursor[b], 1u);
            float val = wv.y * g[s.y];
            sorted[pos] = (__float_as_uint(val) & ~(unsigned)(BSIZE - 1)) |
                          ((unsigned)d.y & (BSIZE - 1));
        }
        {
            unsigned b = ((unsigned)d.z) >> BSHIFT;
            unsigned pos = atomicAdd(&cursor[b], 1u);
            float val = wv.z * g[s.z];
            sorted[pos] = (__float_as_uint(val) & ~(unsigned)(BSIZE - 1)) |
                          ((unsigned)d.z & (BSIZE - 1));
        }
        {
            unsigned b = ((unsigned)d.w) >> BSHIFT;
            unsigned pos = atomicAdd(&cursor[b], 1u);
            float val = wv.w * g[s.w];
            sorted[pos] = (__float_as_uint(val) & ~(unsigned)(BSIZE - 1)) |
                          ((unsigned)d.w & (BSIZE - 1));
        }
    }
    if (blk == nblk - 1) {
        for (int i = G * 4 + tid; i < n_edges; i += 256) {
            int dd = dst[i];
            unsigned b = ((unsigned)dd) >> BSHIFT;
            unsigned pos = atomicAdd(&cursor[b], 1u);
            float val = w[i] * g[src[i]];
            sorted[pos] = (__float_as_uint(val) & ~(unsigned)(BSIZE - 1)) |
                          ((unsigned)dd & (BSIZE - 1));
        }
    }
}

// grid = nb; accumulate one bucket in LDS, fused epilogue.
__global__ void accum_kernel(const unsigned* __restrict__ sorted,
                             const unsigned* __restrict__ base,
                             const unsigned* __restrict__ total,
                             const float* __restrict__ v,
                             const float* __restrict__ stim,
                             const float* __restrict__ vrest,
                             const float* __restrict__ tau,
                             float* __restrict__ out,
                             int n_nodes) {
    __shared__ float acc[BSIZE];
    int b = blockIdx.x, tid = threadIdx.x;
    acc[tid] = 0.0f;
    acc[tid + 256] = 0.0f;
    __syncthreads();
    unsigned start = base[b], n = total[b];
    for (unsigned e = start + tid; e < start + n; e += 256) {
        unsigned u = sorted[e];
        atomicAdd(&acc[u & (BSIZE - 1)],
                  __uint_as_float(u & ~(unsigned)(BSIZE - 1)));
    }
    __syncthreads();
    int node0 = b << BSHIFT;
    for (int l = tid; l < BSIZE; l += 256) {
        int i = node0 + l;
        if (i < n_nodes)
            out[i] = (-v[i] + acc[l] + stim[i] + vrest[i]) / tau[i];
    }
}

// ---------------- fallback (round-1 atomic path) ----------------

__global__ void node_pre_kernel(const float* __restrict__ v,
                                const int* __restrict__ ntype,
                                const float* __restrict__ tp,
                                float* __restrict__ g,
                                float* __restrict__ msg, int n) {
    int i = blockIdx.x * blockDim.x + threadIdx.x;
    if (i < n) {
        float x = v[i];
        x = x > 0.0f ? x : 0.0f;
        g[i] = x * tp[ntype[i]];
        msg[i] = 0.0f;
    }
}

__global__ void edge_scatter_kernel(const int* __restrict__ src,
                                    const int* __restrict__ dst,
                                    const float* __restrict__ w,
                                    const float* __restrict__ g,
                                    float* __restrict__ msg, int n_vec) {
    int i = blockIdx.x * blockDim.x + threadIdx.x;
    if (i < n_vec) {
        int4 s = ((const int4*)src)[i];
        int4 d = ((const int4*)dst)[i];
        float4 wv = ((const float4*)w)[i];
        atomicAdd(&msg[d.x], wv.x * g[s.x]);
        atomicAdd(&msg[d.y], wv.y * g[s.y]);
        atomicAdd(&msg[d.z], wv.z * g[s.z]);
        atomicAdd(&msg[d.w], wv.w * g[s.w]);
    }
}

__global__ void edge_scatter_tail(const int* __restrict__ src,
                                  const int* __restrict__ dst,
                                  const float* __restrict__ w,
                                  const float* __restrict__ g,
                                  float* __restrict__ msg,
                                  int start, int n_edges) {
    int i = start + blockIdx.x * blockDim.x + threadIdx.x;
    if (i < n_edges) atomicAdd(&msg[dst[i]], w[i] * g[src[i]]);
}

__global__ void node_post_kernel(const float* __restrict__ v,
                                 const float* __restrict__ msg,
                                 const float* __restrict__ stim,
                                 const float* __restrict__ vrest,
                                 const float* __restrict__ tau,
                                 float* __restrict__ out, int n) {
    int i = blockIdx.x * blockDim.x + threadIdx.x;
    if (i < n)
        out[i] = (-v[i] + msg[i] + stim[i] + vrest[i]) / tau[i];
}

// ---------------- launch ----------------

extern "C" void kernel_launch(void* const* d_in, const int* in_sizes, int n_in,
                              void* d_out, int out_size, void* d_ws, size_t ws_size,
                              hipStream_t stream) {
    const float* voltage  = (const float*)d_in[0];
    const float* stimulus = (const float*)d_in[1];
    const int*   ntype    = (const int*)d_in[2];
    const int*   edge_idx = (const int*)d_in[3];
    const float* w        = (const float*)d_in[4];
    const float* vrest    = (const float*)d_in[5];
    const float* tau      = (const float*)d_in[6];
    const float* tp       = (const float*)d_in[7];
    float* out = (float*)d_out;

    const int n_nodes = in_sizes[0];
    const int n_edges = in_sizes[4];
    const int* src = edge_idx;
    const int* dst = edge_idx + n_edges;

    const int B = 256;
    const int G = n_edges / 4;                      // int4 groups
    int nblk = (G + GPB - 1) / GPB;
    if (nblk < 1) nblk = 1;
    const int nb = (n_nodes + BSIZE - 1) / BSIZE;   // buckets

    auto align256 = [](size_t x) { return (x + 255) & ~(size_t)255; };
    size_t g_off      = 0;
    size_t sorted_off = align256(g_off + (size_t)n_nodes * 4);
    size_t cnt_off    = align256(sorted_off + (size_t)n_edges * 4);
    size_t total_off  = align256(cnt_off + (size_t)nb * nblk * 4);
    size_t base_off   = align256(total_off + (size_t)nb * 4);
    size_t need       = align256(base_off + (size_t)nb * 4);

    if (nb <= NB_PAD && ws_size >= need) {
        float*    g      = (float*)((char*)d_ws + g_off);
        unsigned* sorted = (unsigned*)((char*)d_ws + sorted_off);
        unsigned* cnt    = (unsigned*)((char*)d_ws + cnt_off);
        unsigned* total  = (unsigned*)((char*)d_ws + total_off);
        unsigned* basep  = (unsigned*)((char*)d_ws + base_off);

        pre_g_kernel<<<(n_nodes + B - 1) / B, B, 0, stream>>>(
            voltage, ntype, tp, g, n_nodes);
        hist_kernel<<<nblk, B, 0, stream>>>(dst, cnt, G, n_edges, nblk, nb);
        scan_blocks_kernel<<<nb, B, 0, stream>>>(cnt, total, nblk);
        scan_buckets_kernel<<<1, B, 0, stream>>>(total, basep, nb);
        scatter_kernel<<<nblk, B, 0, stream>>>(src, dst, w, g, basep, cnt,
                                               sorted, G, n_edges, nblk, nb);
        accum_kernel<<<nb, B, 0, stream>>>(sorted, basep, total, voltage,
                                           stimulus, vrest, tau, out, n_nodes);
    } else {
        // fallback: device-atomic path (correct, ~960 us)
        float* g   = (float*)d_ws;
        float* msg = (float*)d_ws + n_nodes;
        node_pre_kernel<<<(n_nodes + B - 1) / B, B, 0, stream>>>(
            voltage, ntype, tp, g, msg, n_nodes);
        if (G > 0)
            edge_scatter_kernel<<<(G + B - 1) / B, B, 0, stream>>>(
                src, dst, w, g, msg, G);
        if (G * 4 < n_edges) {
            int rem = n_edges - G * 4;
            edge_scatter_tail<<<(rem + B - 1) / B, B, 0, stream>>>(
                src, dst, w, g, msg, G * 4, n_edges);
        }
        node_post_kernel<<<(n_nodes + B - 1) / B, B, 0, stream>>>(
            voltage, msg, stimulus, vrest, tau, out, n_nodes);
    }
}